// Round 12
// baseline (251.379 us; speedup 1.0000x reference)
//
#include <hip/hip_runtime.h>

#define H 1024
#define QD 16
#define BATCH 4
#define SEQ 2048
#define MROWS 8192  // BATCH*SEQ
#define KCH 64      // fused_attn k-chunk

typedef __bf16 bf16x8 __attribute__((ext_vector_type(8)));
typedef __bf16 bf16x4 __attribute__((ext_vector_type(4)));
typedef float f32x4 __attribute__((ext_vector_type(4)));

__device__ __forceinline__ void async_g2l_16(const void* g, void* l) {
  __builtin_amdgcn_global_load_lds(
      (const __attribute__((address_space(1))) unsigned int*)g,
      (__attribute__((address_space(3))) unsigned int*)l, 16, 0, 0);
}

// ---------------- merged prep: cvt_split + 2x transpose + k2_cqk + dvec ----
// All five prep tasks are mutually independent; one launch removes 4 dispatch
// boundaries and overlaps the small latency-bound tasks with cvt_split's
// memory-bound tail. Per-role bodies are bit-identical to the previously
// verified standalone kernels (dvec re-expressed for 256 threads).
// Grid: [0,8192) cvt_split | [8192,10240) transposes (Wv,Wo) |
//       [10240,10752) k2_cqk | 10752 dvec.
__global__ __launch_bounds__(256) void prep_all(
    const float* __restrict__ x, __bf16* __restrict__ xh,
    __bf16* __restrict__ xl, const float* __restrict__ Wv,
    __bf16* __restrict__ Wvt, const float* __restrict__ Wo,
    __bf16* __restrict__ Wot, const float* __restrict__ Wq,
    const float* __restrict__ Wk, const float* __restrict__ We,
    __bf16* __restrict__ Cth, __bf16* __restrict__ Ctl,
    const float* __restrict__ bq, const float* __restrict__ bk,
    const float* __restrict__ be, float* __restrict__ dvec) {
  __shared__ float shbuf[32 * 33];  // transpose tile / dvec partials
  const int bidg = blockIdx.x;

  if (bidg < 8192) {
    // ---- cvt_split: x -> bf16 hi/lo ----
    int i = (bidg * 256 + threadIdx.x) * 4;
    if (i < MROWS * H) {
      float4 f = *(const float4*)(x + i);
      bf16x4 h, l;
      h[0] = (__bf16)f.x; l[0] = (__bf16)(f.x - (float)h[0]);
      h[1] = (__bf16)f.y; l[1] = (__bf16)(f.y - (float)h[1]);
      h[2] = (__bf16)f.z; l[2] = (__bf16)(f.z - (float)h[2]);
      h[3] = (__bf16)f.w; l[3] = (__bf16)(f.w - (float)h[3]);
      *(bf16x4*)(xh + i) = h;
      *(bf16x4*)(xl + i) = l;
    }
  } else if (bidg < 10240) {
    // ---- transpose_cvt_f32_bf16 (which: 0=Wv->Wvt, 1=Wo->Wot), R=C=H ----
    const int id2 = (bidg - 8192) & 1023;
    const int which = (bidg - 8192) >> 10;
    const float* src = which ? Wo : Wv;
    __bf16* dst = which ? Wot : Wvt;
    float (*t)[33] = (float(*)[33])shbuf;
    const int rb = (id2 >> 5) * 32, cb = (id2 & 31) * 32;
    const int c = threadIdx.x & 31;
    const int r0 = threadIdx.x >> 5;
#pragma unroll
    for (int rr = r0; rr < 32; rr += 8)
      t[rr][c] = src[(long)(rb + rr) * H + cb + c];
    __syncthreads();
#pragma unroll
    for (int rr = r0; rr < 32; rr += 8)
      dst[(long)(cb + rr) * H + rb + c] = (__bf16)t[c][rr];
  } else if (bidg < 10752) {
    // ---- k2_cqk: CqkT (Bt layout [32][1024]) in bf16 hi/lo ----
    const int bid2 = bidg - 10240;                  // 0..511
    const int gw = bid2 * 4 + (threadIdx.x >> 6);   // 0..2047
    const int lane = threadIdx.x & 63;
    const int mat = gw & 1, k = gw >> 1;
    const float* Wrow = (mat ? Wk : Wq) + (long)k * H;
    const int col = lane & 15, q4 = lane >> 4;
    const float* wp = Wrow + q4 * 256;
    const float* wep = We + (long)q4 * 256 * QD + col;
    float acc = 0.f;
#pragma unroll 4
    for (int n0 = 0; n0 < 256; n0 += 4) {
      float4 w4 = *(const float4*)(wp + n0);
      acc += w4.x * wep[(n0 + 0) * QD];
      acc += w4.y * wep[(n0 + 1) * QD];
      acc += w4.z * wep[(n0 + 2) * QD];
      acc += w4.w * wep[(n0 + 3) * QD];
    }
    acc += __shfl_xor(acc, 16);
    acc += __shfl_xor(acc, 32);
    if (lane < 16) {
      __bf16 hi = (__bf16)acc;
      __bf16 lo = (__bf16)(acc - (float)hi);
      long idx = (long)(mat * 16 + col) * H + k;
      Cth[idx] = hi;
      Ctl[idx] = lo;
    }
  } else {
    // ---- dvec[j] = (bq|bk)@We + be (256-thread variant) ----
    float* part = shbuf;  // [8][32]
    const int tid = threadIdx.x;
    const int j = tid & 31, p = tid >> 5;  // p 0..7
    const int mat = j >> 4, col = j & 15;
    const float* b = mat ? bk : bq;
    float acc = 0.f;
    for (int n = p * 128; n < p * 128 + 128; ++n) acc += b[n] * We[n * QD + col];
    part[p * 32 + j] = acc;
    __syncthreads();
    if (tid < 32) {
      float sum = be[tid & 15];
      for (int p2 = 0; p2 < 8; ++p2) sum += part[p2 * 32 + tid];
      dvec[tid] = sum;
    }
  }
}

// ---------------- embed via MFMA (hi/lo split), fused normalize ----------------
// v2: 1024 threads, 4-way K-split (each 256-thread group owns a K quarter),
// 4 staging rounds, 4 waves/SIMD. Partials combined via LDS at the end.
// Outputs bf16 qq/kk in [S][32] layout, zero-padded upper half; qq carries
// sqrt(log2 e).
__global__ __launch_bounds__(1024) void k3_embed_mfma(
    const __bf16* __restrict__ xh, const __bf16* __restrict__ xl,
    const __bf16* __restrict__ Cth, const __bf16* __restrict__ Ctl,
    const float* __restrict__ dvec, __bf16* __restrict__ qq32,
    __bf16* __restrict__ kk32) {
  __shared__ __bf16 Ah[4][32 * 64];
  __shared__ __bf16 Al[4][32 * 64];
  __shared__ __bf16 Bh[4][32 * 64];
  __shared__ __bf16 Bl[4][32 * 64];
  const int tid = threadIdx.x;
  const int lane = tid & 63;
  const int w = tid >> 6;       // 0..15
  const int kb = w >> 2;        // K quarter this wave computes on
  const int w4 = w & 3;
  const int rowhalf = w4 >> 1;  // 0/1 -> rows 0-15 / 16-31
  const int ntile = w4 & 1;     // 0 -> qq, 1 -> kk
  const int l15 = lane & 15, quad = lane >> 4;
  const long rowBase = (long)blockIdx.x * 32;

  const int half = tid >> 8;       // 0..3
  const int tl = tid & 255;
  const int srow = tl >> 3;        // 0..31
  const int seg = tl & 7;
  const int segsw = (seg ^ (srow & 7)) * 8;
  const long gk = half * 256 + segsw;
  const __bf16* agh = xh + (rowBase + srow) * H + gk;
  const __bf16* agl = xl + (rowBase + srow) * H + gk;
  const __bf16* bgh = Cth + (long)srow * H + gk;
  const __bf16* bgl = Ctl + (long)srow * H + gk;
  __bf16* lah = &Ah[half][srow * 64 + seg * 8];
  __bf16* lal = &Al[half][srow * 64 + seg * 8];
  __bf16* lbh = &Bh[half][srow * 64 + seg * 8];
  __bf16* lbl = &Bl[half][srow * 64 + seg * 8];

  f32x4 acc;
  acc[0] = 0.f; acc[1] = 0.f; acc[2] = 0.f; acc[3] = 0.f;
  const int arow = (rowhalf * 16 + l15) * 64;
  const int brow = (ntile * 16 + l15) * 64;
  const int h7 = l15 & 7;

  for (int k0 = 0; k0 < 256; k0 += 64) {
    async_g2l_16(agh + k0, lah);
    async_g2l_16(agl + k0, lal);
    async_g2l_16(bgh + k0, lbh);
    async_g2l_16(bgl + k0, lbl);
    __syncthreads();
#pragma unroll
    for (int s = 0; s < 2; ++s) {
      const int slot = ((s * 4 + quad) ^ h7) * 8;
      bf16x8 fah = *(const bf16x8*)&Ah[kb][arow + slot];
      bf16x8 fal = *(const bf16x8*)&Al[kb][arow + slot];
      bf16x8 fbh = *(const bf16x8*)&Bh[kb][brow + slot];
      bf16x8 fbl = *(const bf16x8*)&Bl[kb][brow + slot];
      acc = __builtin_amdgcn_mfma_f32_16x16x32_bf16(fah, fbh, acc, 0, 0, 0);
      acc = __builtin_amdgcn_mfma_f32_16x16x32_bf16(fal, fbh, acc, 0, 0, 0);
      acc = __builtin_amdgcn_mfma_f32_16x16x32_bf16(fah, fbl, acc, 0, 0, 0);
    }
    __syncthreads();
  }

  if (kb > 0) ((f32x4*)&Ah[kb][0])[w4 * 64 + lane] = acc;
  __syncthreads();
  if (kb == 0) {
#pragma unroll
    for (int q = 1; q < 4; ++q) {
      f32x4 o = ((const f32x4*)&Ah[q][0])[w4 * 64 + lane];
      acc[0] += o[0]; acc[1] += o[1]; acc[2] += o[2]; acc[3] += o[3];
    }
    const float dv = dvec[ntile * 16 + l15];
    const float osc = ntile ? 1.0f : 1.20112240878f;  // sqrt(log2 e) into qq
    __bf16* outp = ntile ? kk32 : qq32;
#pragma unroll
    for (int r = 0; r < 4; ++r) {
      float z = acc[r] + dv;
      float s2 = z * z;
      s2 += __shfl_xor(s2, 1);
      s2 += __shfl_xor(s2, 2);
      s2 += __shfl_xor(s2, 4);
      s2 += __shfl_xor(s2, 8);
      float val = z * rsqrtf(s2 + 1e-8f) * osc;
      long row = rowBase + rowhalf * 16 + quad * 4 + r;
      outp[row * 32 + l15] = (__bf16)val;
      outp[row * 32 + 16 + l15] = (__bf16)0.f;  // zero pad K 16->32
    }
  }
}

// ---------------- fused attention, 8 waves, 128q x 256h tile ----------------
// EXACT R6/R11-benched structure (53.7-53.9us, best measured): KCH=64, V
// TRIPLE-buffered (3x32KB) via global_load_lds w/ pre-swizzled source, P
// DOUBLE-buffered (16B-granule XOR swizzle). ONE s_barrier per chunk, counted
// s_waitcnt vmcnt(6). XCD remap: 16 (b,h) panels -> 2/XCD, 1MB V panel
// L2-resident (FETCH 70->9MB verified R6). Buffer safety: stage(t)->buf
// (t+1)%3; PV(t) reads buf t%3; P halves alternate; fast waves blocked by
// barrier(t+1). setprio rejected (R10: +6.3us).
__global__ __launch_bounds__(512) void fused_attn(
    const __bf16* __restrict__ qq32, const __bf16* __restrict__ kk32,
    const __bf16* __restrict__ v_t, __bf16* __restrict__ attn) {
  __shared__ __bf16 Vlds[3][256 * KCH];  // 96KB
  __shared__ __bf16 Plds[2][128 * KCH];  // 32KB
  __shared__ float rsum2[128 * 2];
  const int tid = threadIdx.x;
  const int lane = tid & 63;
  const int w = tid >> 6;  // 0..7
  const int l15 = lane & 15, quad = lane >> 4;
  const int ws_k = w & 1, ws_q = w >> 1;  // S-phase roles
  const int wp_h = w & 3, wp_q = w >> 2;  // PV-phase roles

  // XCD-aware remap: 256 blocks, 8 XCDs, 16 (b,h) panels -> 2 panels/XCD.
  const int bid = blockIdx.x;             // 0..255
  const int xcd = bid & 7, s = bid >> 3;  // s: 0..31
  const int panel = xcd * 2 + (s >> 4);   // 0..15
  const int b = panel >> 2;
  const long hbase = (long)(panel & 3) * 256;
  const long qbase = (long)(s & 15) * 128;

  // qq B-frags: 2, constant across the k-loop
  bf16x8 bq[2];
  {
    const __bf16* qqp =
        qq32 + ((long)b * SEQ + qbase + ws_q * 32 + l15) * 32 + quad * 8;
    bq[0] = *(const bf16x8*)qqp;
    bq[1] = *(const bf16x8*)(qqp + 16 * 32);
  }
  const __bf16* kkb = kk32 + ((long)b * SEQ + ws_k * 32 + l15) * 32 + quad * 8;

  // V staging: linear LDS dest (tid*16B), pre-swizzled global source.
  const int vR = tid >> 3;               // 0..63
  const int vSL = (tid & 7) ^ (vR & 7);  // swizzled global 16B-granule
  const __bf16* vgbase = v_t + (long)b * H * SEQ + (hbase + vR) * SEQ + vSL * 8;

  f32x4 acc[4][4];
#pragma unroll
  for (int i = 0; i < 4; ++i)
#pragma unroll
    for (int j = 0; j < 4; ++j) {
      acc[i][j][0] = 0.f; acc[i][j][1] = 0.f; acc[i][j][2] = 0.f; acc[i][j][3] = 0.f;
    }
  float rsPart[2] = {0.f, 0.f};

  // prologue: stage chunk 0 -> buf0 (4 vmem), load kk frags chunk 0 (2 vmem)
#pragma unroll
  for (int j = 0; j < 4; ++j)
    async_g2l_16(vgbase + (long)j * 64 * SEQ, &Vlds[0][j * 64 * KCH + tid * 8]);
  bf16x8 ak[2];
  ak[0] = *(const bf16x8*)kkb;
  ak[1] = *(const bf16x8*)(kkb + 16 * 32);

  int vcur = 0, vnxt = 1;
  for (int t = 0; t < SEQ / KCH; ++t) {
    const int kn = ((t + 1) & (SEQ / KCH - 1)) * KCH;  // wraps (dummy) at last
    // 1) issue stage of chunk t+1 (4 vmem ops)
#pragma unroll
    for (int j = 0; j < 4; ++j)
      async_g2l_16(vgbase + (long)j * 64 * SEQ + kn,
                   &Vlds[vnxt][j * 64 * KCH + tid * 8]);

    // 2) S-phase (chunk t): 4 MFMAs from regs -> exp2 -> Plds[t&1]
    __bf16* Pw = Plds[t & 1];
#pragma unroll
    for (int i = 0; i < 2; ++i) {
#pragma unroll
      for (int n = 0; n < 2; ++n) {
        f32x4 s2v;
        s2v[0] = 0.f; s2v[1] = 0.f; s2v[2] = 0.f; s2v[3] = 0.f;
        s2v = __builtin_amdgcn_mfma_f32_16x16x32_bf16(ak[i], bq[n], s2v, 0, 0, 0);
        bf16x4 pw;
        float part = 0.f;
#pragma unroll
        for (int r = 0; r < 4; ++r) {
          float wgt = exp2f(s2v[r] * s2v[r]);  // qq carries sqrt(log2e)
          part += wgt;
          pw[r] = (__bf16)wgt;
        }
        rsPart[n] += part;
        const int q = ws_q * 32 + n * 16 + l15;
        const int g = ws_k * 4 + i * 2 + (quad >> 1);
        *(bf16x4*)&Pw[q * KCH + ((g ^ (q & 7)) << 3) + (quad & 1) * 4] = pw;
      }
    }
    // 3) prefetch kk frags for chunk t+1 (2 vmem ops)
    ak[0] = *(const bf16x8*)(kkb + (long)kn * 32);
    ak[1] = *(const bf16x8*)(kkb + (long)(kn + 16) * 32);

    // 4) P writes visible; chunk-t V staged (6 younger vmem stay in flight)
    asm volatile("s_waitcnt lgkmcnt(0)" ::: "memory");
    asm volatile("s_waitcnt vmcnt(6)" ::: "memory");
    __builtin_amdgcn_sched_barrier(0);
    __builtin_amdgcn_s_barrier();

    // 5) PV: acc += P[128q x 64k] @ V[256h x 64k]^T   (wave: 64q x 64h)
    const __bf16* Vr = Vlds[vcur];
#pragma unroll
    for (int ks = 0; ks < 2; ++ks) {
      bf16x8 ap[4], bv[4];
#pragma unroll
      for (int i = 0; i < 4; ++i) {
        const int q = wp_q * 64 + i * 16 + l15;
        ap[i] = *(const bf16x8*)&Pw[q * KCH + (((ks * 4 + quad) ^ (q & 7)) << 3)];
      }
#pragma unroll
      for (int j = 0; j < 4; ++j) {
        const int vr = wp_h * 64 + j * 16 + l15;
        bv[j] = *(const bf16x8*)&Vr[vr * KCH + (((ks * 4 + quad) ^ (vr & 7)) << 3)];
      }
#pragma unroll
      for (int i = 0; i < 4; ++i)
#pragma unroll
        for (int j = 0; j < 4; ++j)
          acc[i][j] =
              __builtin_amdgcn_mfma_f32_16x16x32_bf16(ap[i], bv[j], acc[i][j], 0, 0, 0);
    }
    // 6) rotate V buffers (no second barrier needed: see header comment)
    const int third = 3 - vcur - vnxt;
    vcur = vnxt;
    vnxt = third;
  }

  // rowsum: reduce lane partials over quads, combine two k-halves via LDS
#pragma unroll
  for (int n = 0; n < 2; ++n) {
    float vs = rsPart[n];
    vs += __shfl_xor(vs, 16);
    vs += __shfl_xor(vs, 32);
    if (lane < 16) rsum2[(ws_q * 32 + n * 16 + l15) * 2 + ws_k] = vs;
  }
  __syncthreads();  // also drains the final dummy stage

  float rinv[4][4];
#pragma unroll
  for (int i = 0; i < 4; ++i)
#pragma unroll
    for (int r = 0; r < 4; ++r) {
      int row = wp_q * 64 + i * 16 + quad * 4 + r;
      rinv[i][r] = 1.0f / (rsum2[row * 2] + rsum2[row * 2 + 1]);
    }

  __bf16* ob = attn + ((long)b * SEQ + qbase) * H + hbase;
#pragma unroll
  for (int i = 0; i < 4; ++i)
#pragma unroll
    for (int j = 0; j < 4; ++j) {
      const int colL = wp_h * 64 + j * 16 + l15;
#pragma unroll
      for (int r = 0; r < 4; ++r) {
        const int rowL = wp_q * 64 + i * 16 + quad * 4 + r;
        ob[(long)rowL * H + colL] = (__bf16)(acc[i][j][r] * rinv[i][r]);
      }
    }
}

// ---------------- m97-style GEMM + XOR-swizzled LDS: C = A @ Bt^T (+bias) ----
// v2 (R7-benched): XCD-aware block remap (T1). Grid must be (8, 64): each XCD
// gets 8 contiguous row-panels x all 8 col-blocks -> each 256KB A-panel lives
// in exactly one XCD's L2.
// OUTMODE: 0 = fp32 row-major, 1 = bf16 row-major, 2 = bf16 transposed batched
//          (Cout layout [BATCH][N][SEQ], rows are per-batch: row = b*SEQ + rb)
template <int OUTMODE, int HASBIAS>
__global__ __launch_bounds__(256) void gemm_bt(
    const __bf16* __restrict__ A, const __bf16* __restrict__ Bt,
    void* __restrict__ Cout, const float* __restrict__ bias, int M, int N, int K) {
  __shared__ __bf16 Alds[128 * 64];
  __shared__ __bf16 Blds[128 * 64];
  const int tid = threadIdx.x;
  const int lane = tid & 63;
  const int w = tid >> 6;
  const int wm = w >> 1, wn = w & 1;
  const int l15 = lane & 15, quad = lane >> 4;

  // XCD remap (grid == (8,64), 512 blocks, round-robin dispatch):
  const int flat = blockIdx.y * 8 + blockIdx.x;  // 0..511
  const int xcd = flat & 7, idx = flat >> 3;     // idx 0..63
  const int rowPanel = xcd * 8 + (idx >> 3);     // 0..63
  const int colBlk = idx & 7;                    // 0..7
  const long rowBase = (long)rowPanel * 128;
  const long colBase = (long)colBlk * 128;

  const int srow = lane >> 3;                 // 0..7
  const int segsw = ((lane & 7) ^ srow) * 8;  // swizzled global k-seg

  const __bf16* ag[4];
  const __bf16* bg[4];
  __bf16* as_[4];
  __bf16* bs_[4];
#pragma unroll
  for (int j = 0; j < 4; ++j) {
    int r = j * 32 + w * 8;
    ag[j] = A + (rowBase + r + srow) * (long)K + segsw;
    bg[j] = Bt + (colBase + r + srow) * (long)K + segsw;
    as_[j] = &Alds[r * 64 + (lane & 7) * 8];
    bs_[j] = &Blds[r * 64 + (lane & 7) * 8];
  }

  f32x4 acc[4][4];
#pragma unroll
  for (int i = 0; i < 4; ++i)
#pragma unroll
    for (int j = 0; j < 4; ++j) {
      acc[i][j][0] = 0.f; acc[i][j][1] = 0.f; acc[i][j][2] = 0.f; acc[i][j][3] = 0.f;
    }

  const int h7 = l15 & 7;

  for (int k0 = 0; k0 < K; k0 += 64) {
#pragma unroll
    for (int j = 0; j < 4; ++j) {
      async_g2l_16(ag[j], as_[j]);
      async_g2l_16(bg[j], bs_[j]);
      ag[j] += 64;
      bg[j] += 64;
    }
    __syncthreads();
#pragma unroll
    for (int s = 0; s < 2; ++s) {
      const int slot = ((s * 4 + quad) ^ h7) * 8;
      bf16x8 af[4], bfv[4];
#pragma unroll
      for (int i = 0; i < 4; ++i) {
        af[i] = *(const bf16x8*)&Alds[(wm * 64 + i * 16 + l15) * 64 + slot];
        bfv[i] = *(const bf16x8*)&Blds[(wn * 64 + i * 16 + l15) * 64 + slot];
      }
#pragma unroll
      for (int i = 0; i < 4; ++i)
#pragma unroll
        for (int j = 0; j < 4; ++j)
          acc[i][j] =
              __builtin_amdgcn_mfma_f32_16x16x32_bf16(af[i], bfv[j], acc[i][j], 0, 0, 0);
    }
    __syncthreads();
  }

  const long crow0 = rowBase + wm * 64 + quad * 4;
  const long ccol0 = colBase + wn * 64 + l15;
#pragma unroll
  for (int i = 0; i < 4; ++i) {
#pragma unroll
    for (int j = 0; j < 4; ++j) {
      long col = ccol0 + j * 16;
      float bb = HASBIAS ? bias[col] : 0.f;
      if (OUTMODE == 2) {
        long row0 = crow0 + i * 16;          // 4 consecutive rows, same batch
        int bz = (int)(row0 >> 11);          // row / SEQ
        long rb = row0 & (SEQ - 1);
        bf16x4 pv;
#pragma unroll
        for (int r = 0; r < 4; ++r) pv[r] = (__bf16)(acc[i][j][r] + bb);
        *(bf16x4*)&((__bf16*)Cout)[((long)bz * N + col) * SEQ + rb] = pv;
      } else {
#pragma unroll
        for (int r = 0; r < 4; ++r) {
          long row = crow0 + i * 16 + r;
          float val = acc[i][j][r] + bb;
          if (OUTMODE == 0)
            ((float*)Cout)[row * N + col] = val;
          else
            ((__bf16*)Cout)[row * N + col] = (__bf16)val;
        }
      }
    }
  }
}

extern "C" void kernel_launch(void* const* d_in, const int* in_sizes, int n_in,
                              void* d_out, int out_size, void* d_ws, size_t ws_size,
                              hipStream_t stream) {
  const float* x = (const float*)d_in[0];
  const float* Wq = (const float*)d_in[1];
  const float* bq = (const float*)d_in[2];
  const float* Wk = (const float*)d_in[3];
  const float* bk = (const float*)d_in[4];
  const float* Wv = (const float*)d_in[5];
  const float* bv = (const float*)d_in[6];
  const float* We = (const float*)d_in[7];
  const float* be = (const float*)d_in[8];
  const float* Wo = (const float*)d_in[9];
  const float* bo = (const float*)d_in[10];
  float* out = (float*)d_out;

  char* ws = (char*)d_ws;
  size_t o = 0;
  auto alloc = [&](size_t n) {
    size_t r = o;
    o += (n + 255) & ~(size_t)255;
    return r;
  };
  __bf16* xbf = (__bf16*)(ws + alloc((size_t)MROWS * H * 2));  // x hi
  __bf16* v_t = (__bf16*)(ws + alloc((size_t)MROWS * H * 2));  // v^T [B][H][S]
  __bf16* attn = (__bf16*)(ws + alloc((size_t)MROWS * H * 2));
  __bf16* Wvt = (__bf16*)(ws + alloc((size_t)H * H * 2));
  __bf16* Wot = (__bf16*)(ws + alloc((size_t)H * H * 2));
  __bf16* Cth = (__bf16*)(ws + alloc((size_t)32 * H * 2));
  __bf16* Ctl = (__bf16*)(ws + alloc((size_t)32 * H * 2));
  float* dvec = (float*)(ws + alloc(32 * 4));
  __bf16* qq32 = (__bf16*)(ws + alloc((size_t)MROWS * 32 * 2));
  __bf16* kk32 = (__bf16*)(ws + alloc((size_t)MROWS * 32 * 2));
  // Alias (stream-ordered lifetime separation):
  __bf16* xlo = attn;  // x lo part: dead before attn is written (fused_attn)
  if (ws_size < o) return;

  // 1) merged prep: cvt_split + Wv^T + Wo^T + CqkT + dvec (one launch)
  prep_all<<<10753, 256, 0, stream>>>(x, xbf, xlo, Wv, Wvt, Wo, Wot, Wq, Wk,
                                      We, Cth, Ctl, bq, bk, be, dvec);
  // 2) unit-norm quantum embeds via MFMA (4-way K-split, 16 waves)
  k3_embed_mfma<<<MROWS / 32, 1024, 0, stream>>>(xbf, xlo, Cth, Ctl, dvec, qq32, kk32);
  // 3) v = x@Wv + bv, written TRANSPOSED per batch -> v_t[b][h][s]
  gemm_bt<2, 1><<<dim3(8, 64), 256, 0, stream>>>(xbf, Wvt, v_t, bv, MROWS, H, H);
  // 4) fused: S^T once per 256h -> exp2(S'^2) -> P@v/rowsum (8 waves)
  fused_attn<<<256, 512, 0, stream>>>(qq32, kk32, v_t, attn);
  // 5) out = attended @ Wo + bo  (fp32 out)
  gemm_bt<0, 1><<<dim3(8, 64), 256, 0, stream>>>(attn, Wot, out, bo, MROWS, H, H);
}

// Round 13
// 240.073 us; speedup vs baseline: 1.0471x; 1.0471x over previous
//
#include <hip/hip_runtime.h>

#define H 1024
#define QD 16
#define BATCH 4
#define SEQ 2048
#define MROWS 8192  // BATCH*SEQ
#define KCH 64      // fused_attn k-chunk

typedef __bf16 bf16x8 __attribute__((ext_vector_type(8)));
typedef __bf16 bf16x4 __attribute__((ext_vector_type(4)));
typedef float f32x4 __attribute__((ext_vector_type(4)));

__device__ __forceinline__ void async_g2l_16(const void* g, void* l) {
  __builtin_amdgcn_global_load_lds(
      (const __attribute__((address_space(1))) unsigned int*)g,
      (__attribute__((address_space(3))) unsigned int*)l, 16, 0, 0);
}

// ---------------- merged prep v2: reordered grid + 16B cvt stores ----------
// R12 lesson: long-latency low-parallelism roles (k2_cqk, dvec) were at the
// grid TAIL -> ~15us near-idle drain. Now they're FIRST so they overlap the
// streaming flood. cvt role now 8 elem/thread (2x float4 load, bf16x8 16B
// stores) per G13. Roles:
//   [0,512)      k2_cqk   (long serial loops)
//   512          dvec     (single block)
//   [513,2561)   transposes (Wv,Wo)
//   [2561,6657)  cvt_split bulk streaming
__global__ __launch_bounds__(256) void prep_all(
    const float* __restrict__ x, __bf16* __restrict__ xh,
    __bf16* __restrict__ xl, const float* __restrict__ Wv,
    __bf16* __restrict__ Wvt, const float* __restrict__ Wo,
    __bf16* __restrict__ Wot, const float* __restrict__ Wq,
    const float* __restrict__ Wk, const float* __restrict__ We,
    __bf16* __restrict__ Cth, __bf16* __restrict__ Ctl,
    const float* __restrict__ bq, const float* __restrict__ bk,
    const float* __restrict__ be, float* __restrict__ dvec) {
  __shared__ float shbuf[32 * 33];  // transpose tile / dvec partials
  const int bidg = blockIdx.x;

  if (bidg < 512) {
    // ---- k2_cqk: CqkT (Bt layout [32][1024]) in bf16 hi/lo ----
    const int gw = bidg * 4 + (threadIdx.x >> 6);   // 0..2047
    const int lane = threadIdx.x & 63;
    const int mat = gw & 1, k = gw >> 1;
    const float* Wrow = (mat ? Wk : Wq) + (long)k * H;
    const int col = lane & 15, q4 = lane >> 4;
    const float* wp = Wrow + q4 * 256;
    const float* wep = We + (long)q4 * 256 * QD + col;
    float acc = 0.f;
#pragma unroll 4
    for (int n0 = 0; n0 < 256; n0 += 4) {
      float4 w4 = *(const float4*)(wp + n0);
      acc += w4.x * wep[(n0 + 0) * QD];
      acc += w4.y * wep[(n0 + 1) * QD];
      acc += w4.z * wep[(n0 + 2) * QD];
      acc += w4.w * wep[(n0 + 3) * QD];
    }
    acc += __shfl_xor(acc, 16);
    acc += __shfl_xor(acc, 32);
    if (lane < 16) {
      __bf16 hi = (__bf16)acc;
      __bf16 lo = (__bf16)(acc - (float)hi);
      long idx = (long)(mat * 16 + col) * H + k;
      Cth[idx] = hi;
      Ctl[idx] = lo;
    }
  } else if (bidg == 512) {
    // ---- dvec[j] = (bq|bk)@We + be (256-thread variant) ----
    float* part = shbuf;  // [8][32]
    const int tid = threadIdx.x;
    const int j = tid & 31, p = tid >> 5;  // p 0..7
    const int mat = j >> 4, col = j & 15;
    const float* b = mat ? bk : bq;
    float acc = 0.f;
    for (int n = p * 128; n < p * 128 + 128; ++n) acc += b[n] * We[n * QD + col];
    part[p * 32 + j] = acc;
    __syncthreads();
    if (tid < 32) {
      float sum = be[tid & 15];
      for (int p2 = 0; p2 < 8; ++p2) sum += part[p2 * 32 + tid];
      dvec[tid] = sum;
    }
  } else if (bidg < 2561) {
    // ---- transpose_cvt_f32_bf16 (which: 0=Wv->Wvt, 1=Wo->Wot), R=C=H ----
    const int id = bidg - 513;
    const int id2 = id & 1023;
    const int which = id >> 10;
    const float* src = which ? Wo : Wv;
    __bf16* dst = which ? Wot : Wvt;
    float (*t)[33] = (float(*)[33])shbuf;
    const int rb = (id2 >> 5) * 32, cb = (id2 & 31) * 32;
    const int c = threadIdx.x & 31;
    const int r0 = threadIdx.x >> 5;
#pragma unroll
    for (int rr = r0; rr < 32; rr += 8)
      t[rr][c] = src[(long)(rb + rr) * H + cb + c];
    __syncthreads();
#pragma unroll
    for (int rr = r0; rr < 32; rr += 8)
      dst[(long)(cb + rr) * H + rb + c] = (__bf16)t[c][rr];
  } else {
    // ---- cvt_split: x -> bf16 hi/lo, 8 elem/thread, 16B stores ----
    const int bidc = bidg - 2561;  // 0..4095
    long i = ((long)bidc * 256 + threadIdx.x) * 8;
    float v[8];
    *(float4*)&v[0] = *(const float4*)(x + i);
    *(float4*)&v[4] = *(const float4*)(x + i + 4);
    bf16x8 h, l;
#pragma unroll
    for (int e = 0; e < 8; ++e) {
      __bf16 hh = (__bf16)v[e];
      h[e] = hh;
      l[e] = (__bf16)(v[e] - (float)hh);
    }
    *(bf16x8*)(xh + i) = h;
    *(bf16x8*)(xl + i) = l;
  }
}

// ---------------- embed via MFMA (hi/lo split), fused normalize ----------------
// v2: 1024 threads, 4-way K-split (each 256-thread group owns a K quarter),
// 4 staging rounds, 4 waves/SIMD. Partials combined via LDS at the end.
// Outputs bf16 qq/kk in [S][32] layout, zero-padded upper half; qq carries
// sqrt(log2 e).
__global__ __launch_bounds__(1024) void k3_embed_mfma(
    const __bf16* __restrict__ xh, const __bf16* __restrict__ xl,
    const __bf16* __restrict__ Cth, const __bf16* __restrict__ Ctl,
    const float* __restrict__ dvec, __bf16* __restrict__ qq32,
    __bf16* __restrict__ kk32) {
  __shared__ __bf16 Ah[4][32 * 64];
  __shared__ __bf16 Al[4][32 * 64];
  __shared__ __bf16 Bh[4][32 * 64];
  __shared__ __bf16 Bl[4][32 * 64];
  const int tid = threadIdx.x;
  const int lane = tid & 63;
  const int w = tid >> 6;       // 0..15
  const int kb = w >> 2;        // K quarter this wave computes on
  const int w4 = w & 3;
  const int rowhalf = w4 >> 1;  // 0/1 -> rows 0-15 / 16-31
  const int ntile = w4 & 1;     // 0 -> qq, 1 -> kk
  const int l15 = lane & 15, quad = lane >> 4;
  const long rowBase = (long)blockIdx.x * 32;

  const int half = tid >> 8;       // 0..3
  const int tl = tid & 255;
  const int srow = tl >> 3;        // 0..31
  const int seg = tl & 7;
  const int segsw = (seg ^ (srow & 7)) * 8;
  const long gk = half * 256 + segsw;
  const __bf16* agh = xh + (rowBase + srow) * H + gk;
  const __bf16* agl = xl + (rowBase + srow) * H + gk;
  const __bf16* bgh = Cth + (long)srow * H + gk;
  const __bf16* bgl = Ctl + (long)srow * H + gk;
  __bf16* lah = &Ah[half][srow * 64 + seg * 8];
  __bf16* lal = &Al[half][srow * 64 + seg * 8];
  __bf16* lbh = &Bh[half][srow * 64 + seg * 8];
  __bf16* lbl = &Bl[half][srow * 64 + seg * 8];

  f32x4 acc;
  acc[0] = 0.f; acc[1] = 0.f; acc[2] = 0.f; acc[3] = 0.f;
  const int arow = (rowhalf * 16 + l15) * 64;
  const int brow = (ntile * 16 + l15) * 64;
  const int h7 = l15 & 7;

  for (int k0 = 0; k0 < 256; k0 += 64) {
    async_g2l_16(agh + k0, lah);
    async_g2l_16(agl + k0, lal);
    async_g2l_16(bgh + k0, lbh);
    async_g2l_16(bgl + k0, lbl);
    __syncthreads();
#pragma unroll
    for (int s = 0; s < 2; ++s) {
      const int slot = ((s * 4 + quad) ^ h7) * 8;
      bf16x8 fah = *(const bf16x8*)&Ah[kb][arow + slot];
      bf16x8 fal = *(const bf16x8*)&Al[kb][arow + slot];
      bf16x8 fbh = *(const bf16x8*)&Bh[kb][brow + slot];
      bf16x8 fbl = *(const bf16x8*)&Bl[kb][brow + slot];
      acc = __builtin_amdgcn_mfma_f32_16x16x32_bf16(fah, fbh, acc, 0, 0, 0);
      acc = __builtin_amdgcn_mfma_f32_16x16x32_bf16(fal, fbh, acc, 0, 0, 0);
      acc = __builtin_amdgcn_mfma_f32_16x16x32_bf16(fah, fbl, acc, 0, 0, 0);
    }
    __syncthreads();
  }

  if (kb > 0) ((f32x4*)&Ah[kb][0])[w4 * 64 + lane] = acc;
  __syncthreads();
  if (kb == 0) {
#pragma unroll
    for (int q = 1; q < 4; ++q) {
      f32x4 o = ((const f32x4*)&Ah[q][0])[w4 * 64 + lane];
      acc[0] += o[0]; acc[1] += o[1]; acc[2] += o[2]; acc[3] += o[3];
    }
    const float dv = dvec[ntile * 16 + l15];
    const float osc = ntile ? 1.0f : 1.20112240878f;  // sqrt(log2 e) into qq
    __bf16* outp = ntile ? kk32 : qq32;
#pragma unroll
    for (int r = 0; r < 4; ++r) {
      float z = acc[r] + dv;
      float s2 = z * z;
      s2 += __shfl_xor(s2, 1);
      s2 += __shfl_xor(s2, 2);
      s2 += __shfl_xor(s2, 4);
      s2 += __shfl_xor(s2, 8);
      float val = z * rsqrtf(s2 + 1e-8f) * osc;
      long row = rowBase + rowhalf * 16 + quad * 4 + r;
      outp[row * 32 + l15] = (__bf16)val;
      outp[row * 32 + 16 + l15] = (__bf16)0.f;  // zero pad K 16->32
    }
  }
}

// ---------------- fused attention, 8 waves, 128q x 256h tile ----------------
// EXACT R6/R11-benched structure (53.7-53.9us, best measured): KCH=64, V
// TRIPLE-buffered (3x32KB) via global_load_lds w/ pre-swizzled source, P
// DOUBLE-buffered (16B-granule XOR swizzle). ONE s_barrier per chunk, counted
// s_waitcnt vmcnt(6). XCD remap: 16 (b,h) panels -> 2/XCD, 1MB V panel
// L2-resident (FETCH 70->9MB verified R6). Buffer safety: stage(t)->buf
// (t+1)%3; PV(t) reads buf t%3; P halves alternate; fast waves blocked by
// barrier(t+1). setprio rejected (R10: +6.3us).
__global__ __launch_bounds__(512) void fused_attn(
    const __bf16* __restrict__ qq32, const __bf16* __restrict__ kk32,
    const __bf16* __restrict__ v_t, __bf16* __restrict__ attn) {
  __shared__ __bf16 Vlds[3][256 * KCH];  // 96KB
  __shared__ __bf16 Plds[2][128 * KCH];  // 32KB
  __shared__ float rsum2[128 * 2];
  const int tid = threadIdx.x;
  const int lane = tid & 63;
  const int w = tid >> 6;  // 0..7
  const int l15 = lane & 15, quad = lane >> 4;
  const int ws_k = w & 1, ws_q = w >> 1;  // S-phase roles
  const int wp_h = w & 3, wp_q = w >> 2;  // PV-phase roles

  // XCD-aware remap: 256 blocks, 8 XCDs, 16 (b,h) panels -> 2 panels/XCD.
  const int bid = blockIdx.x;             // 0..255
  const int xcd = bid & 7, s = bid >> 3;  // s: 0..31
  const int panel = xcd * 2 + (s >> 4);   // 0..15
  const int b = panel >> 2;
  const long hbase = (long)(panel & 3) * 256;
  const long qbase = (long)(s & 15) * 128;

  // qq B-frags: 2, constant across the k-loop
  bf16x8 bq[2];
  {
    const __bf16* qqp =
        qq32 + ((long)b * SEQ + qbase + ws_q * 32 + l15) * 32 + quad * 8;
    bq[0] = *(const bf16x8*)qqp;
    bq[1] = *(const bf16x8*)(qqp + 16 * 32);
  }
  const __bf16* kkb = kk32 + ((long)b * SEQ + ws_k * 32 + l15) * 32 + quad * 8;

  // V staging: linear LDS dest (tid*16B), pre-swizzled global source.
  const int vR = tid >> 3;               // 0..63
  const int vSL = (tid & 7) ^ (vR & 7);  // swizzled global 16B-granule
  const __bf16* vgbase = v_t + (long)b * H * SEQ + (hbase + vR) * SEQ + vSL * 8;

  f32x4 acc[4][4];
#pragma unroll
  for (int i = 0; i < 4; ++i)
#pragma unroll
    for (int j = 0; j < 4; ++j) {
      acc[i][j][0] = 0.f; acc[i][j][1] = 0.f; acc[i][j][2] = 0.f; acc[i][j][3] = 0.f;
    }
  float rsPart[2] = {0.f, 0.f};

  // prologue: stage chunk 0 -> buf0 (4 vmem), load kk frags chunk 0 (2 vmem)
#pragma unroll
  for (int j = 0; j < 4; ++j)
    async_g2l_16(vgbase + (long)j * 64 * SEQ, &Vlds[0][j * 64 * KCH + tid * 8]);
  bf16x8 ak[2];
  ak[0] = *(const bf16x8*)kkb;
  ak[1] = *(const bf16x8*)(kkb + 16 * 32);

  int vcur = 0, vnxt = 1;
  for (int t = 0; t < SEQ / KCH; ++t) {
    const int kn = ((t + 1) & (SEQ / KCH - 1)) * KCH;  // wraps (dummy) at last
    // 1) issue stage of chunk t+1 (4 vmem ops)
#pragma unroll
    for (int j = 0; j < 4; ++j)
      async_g2l_16(vgbase + (long)j * 64 * SEQ + kn,
                   &Vlds[vnxt][j * 64 * KCH + tid * 8]);

    // 2) S-phase (chunk t): 4 MFMAs from regs -> exp2 -> Plds[t&1]
    __bf16* Pw = Plds[t & 1];
#pragma unroll
    for (int i = 0; i < 2; ++i) {
#pragma unroll
      for (int n = 0; n < 2; ++n) {
        f32x4 s2v;
        s2v[0] = 0.f; s2v[1] = 0.f; s2v[2] = 0.f; s2v[3] = 0.f;
        s2v = __builtin_amdgcn_mfma_f32_16x16x32_bf16(ak[i], bq[n], s2v, 0, 0, 0);
        bf16x4 pw;
        float part = 0.f;
#pragma unroll
        for (int r = 0; r < 4; ++r) {
          float wgt = exp2f(s2v[r] * s2v[r]);  // qq carries sqrt(log2e)
          part += wgt;
          pw[r] = (__bf16)wgt;
        }
        rsPart[n] += part;
        const int q = ws_q * 32 + n * 16 + l15;
        const int g = ws_k * 4 + i * 2 + (quad >> 1);
        *(bf16x4*)&Pw[q * KCH + ((g ^ (q & 7)) << 3) + (quad & 1) * 4] = pw;
      }
    }
    // 3) prefetch kk frags for chunk t+1 (2 vmem ops)
    ak[0] = *(const bf16x8*)(kkb + (long)kn * 32);
    ak[1] = *(const bf16x8*)(kkb + (long)(kn + 16) * 32);

    // 4) P writes visible; chunk-t V staged (6 younger vmem stay in flight)
    asm volatile("s_waitcnt lgkmcnt(0)" ::: "memory");
    asm volatile("s_waitcnt vmcnt(6)" ::: "memory");
    __builtin_amdgcn_sched_barrier(0);
    __builtin_amdgcn_s_barrier();

    // 5) PV: acc += P[128q x 64k] @ V[256h x 64k]^T   (wave: 64q x 64h)
    const __bf16* Vr = Vlds[vcur];
#pragma unroll
    for (int ks = 0; ks < 2; ++ks) {
      bf16x8 ap[4], bv[4];
#pragma unroll
      for (int i = 0; i < 4; ++i) {
        const int q = wp_q * 64 + i * 16 + l15;
        ap[i] = *(const bf16x8*)&Pw[q * KCH + (((ks * 4 + quad) ^ (q & 7)) << 3)];
      }
#pragma unroll
      for (int j = 0; j < 4; ++j) {
        const int vr = wp_h * 64 + j * 16 + l15;
        bv[j] = *(const bf16x8*)&Vr[vr * KCH + (((ks * 4 + quad) ^ (vr & 7)) << 3)];
      }
#pragma unroll
      for (int i = 0; i < 4; ++i)
#pragma unroll
        for (int j = 0; j < 4; ++j)
          acc[i][j] =
              __builtin_amdgcn_mfma_f32_16x16x32_bf16(ap[i], bv[j], acc[i][j], 0, 0, 0);
    }
    // 6) rotate V buffers (no second barrier needed: see header comment)
    const int third = 3 - vcur - vnxt;
    vcur = vnxt;
    vnxt = third;
  }

  // rowsum: reduce lane partials over quads, combine two k-halves via LDS
#pragma unroll
  for (int n = 0; n < 2; ++n) {
    float vs = rsPart[n];
    vs += __shfl_xor(vs, 16);
    vs += __shfl_xor(vs, 32);
    if (lane < 16) rsum2[(ws_q * 32 + n * 16 + l15) * 2 + ws_k] = vs;
  }
  __syncthreads();  // also drains the final dummy stage

  float rinv[4][4];
#pragma unroll
  for (int i = 0; i < 4; ++i)
#pragma unroll
    for (int r = 0; r < 4; ++r) {
      int row = wp_q * 64 + i * 16 + quad * 4 + r;
      rinv[i][r] = 1.0f / (rsum2[row * 2] + rsum2[row * 2 + 1]);
    }

  __bf16* ob = attn + ((long)b * SEQ + qbase) * H + hbase;
#pragma unroll
  for (int i = 0; i < 4; ++i)
#pragma unroll
    for (int j = 0; j < 4; ++j) {
      const int colL = wp_h * 64 + j * 16 + l15;
#pragma unroll
      for (int r = 0; r < 4; ++r) {
        const int rowL = wp_q * 64 + i * 16 + quad * 4 + r;
        ob[(long)rowL * H + colL] = (__bf16)(acc[i][j][r] * rinv[i][r]);
      }
    }
}

// ---------------- m97-style GEMM + XOR-swizzled LDS: C = A @ Bt^T (+bias) ----
// v2 (R7-benched): XCD-aware block remap (T1). Grid must be (8, 64): each XCD
// gets 8 contiguous row-panels x all 8 col-blocks -> each 256KB A-panel lives
// in exactly one XCD's L2.
// OUTMODE: 0 = fp32 row-major, 1 = bf16 row-major, 2 = bf16 transposed batched
//          (Cout layout [BATCH][N][SEQ], rows are per-batch: row = b*SEQ + rb)
template <int OUTMODE, int HASBIAS>
__global__ __launch_bounds__(256) void gemm_bt(
    const __bf16* __restrict__ A, const __bf16* __restrict__ Bt,
    void* __restrict__ Cout, const float* __restrict__ bias, int M, int N, int K) {
  __shared__ __bf16 Alds[128 * 64];
  __shared__ __bf16 Blds[128 * 64];
  const int tid = threadIdx.x;
  const int lane = tid & 63;
  const int w = tid >> 6;
  const int wm = w >> 1, wn = w & 1;
  const int l15 = lane & 15, quad = lane >> 4;

  // XCD remap (grid == (8,64), 512 blocks, round-robin dispatch):
  const int flat = blockIdx.y * 8 + blockIdx.x;  // 0..511
  const int xcd = flat & 7, idx = flat >> 3;     // idx 0..63
  const int rowPanel = xcd * 8 + (idx >> 3);     // 0..63
  const int colBlk = idx & 7;                    // 0..7
  const long rowBase = (long)rowPanel * 128;
  const long colBase = (long)colBlk * 128;

  const int srow = lane >> 3;                 // 0..7
  const int segsw = ((lane & 7) ^ srow) * 8;  // swizzled global k-seg

  const __bf16* ag[4];
  const __bf16* bg[4];
  __bf16* as_[4];
  __bf16* bs_[4];
#pragma unroll
  for (int j = 0; j < 4; ++j) {
    int r = j * 32 + w * 8;
    ag[j] = A + (rowBase + r + srow) * (long)K + segsw;
    bg[j] = Bt + (colBase + r + srow) * (long)K + segsw;
    as_[j] = &Alds[r * 64 + (lane & 7) * 8];
    bs_[j] = &Blds[r * 64 + (lane & 7) * 8];
  }

  f32x4 acc[4][4];
#pragma unroll
  for (int i = 0; i < 4; ++i)
#pragma unroll
    for (int j = 0; j < 4; ++j) {
      acc[i][j][0] = 0.f; acc[i][j][1] = 0.f; acc[i][j][2] = 0.f; acc[i][j][3] = 0.f;
    }

  const int h7 = l15 & 7;

  for (int k0 = 0; k0 < K; k0 += 64) {
#pragma unroll
    for (int j = 0; j < 4; ++j) {
      async_g2l_16(ag[j], as_[j]);
      async_g2l_16(bg[j], bs_[j]);
      ag[j] += 64;
      bg[j] += 64;
    }
    __syncthreads();
#pragma unroll
    for (int s = 0; s < 2; ++s) {
      const int slot = ((s * 4 + quad) ^ h7) * 8;
      bf16x8 af[4], bfv[4];
#pragma unroll
      for (int i = 0; i < 4; ++i) {
        af[i] = *(const bf16x8*)&Alds[(wm * 64 + i * 16 + l15) * 64 + slot];
        bfv[i] = *(const bf16x8*)&Blds[(wn * 64 + i * 16 + l15) * 64 + slot];
      }
#pragma unroll
      for (int i = 0; i < 4; ++i)
#pragma unroll
        for (int j = 0; j < 4; ++j)
          acc[i][j] =
              __builtin_amdgcn_mfma_f32_16x16x32_bf16(af[i], bfv[j], acc[i][j], 0, 0, 0);
    }
    __syncthreads();
  }

  const long crow0 = rowBase + wm * 64 + quad * 4;
  const long ccol0 = colBase + wn * 64 + l15;
#pragma unroll
  for (int i = 0; i < 4; ++i) {
#pragma unroll
    for (int j = 0; j < 4; ++j) {
      long col = ccol0 + j * 16;
      float bb = HASBIAS ? bias[col] : 0.f;
      if (OUTMODE == 2) {
        long row0 = crow0 + i * 16;          // 4 consecutive rows, same batch
        int bz = (int)(row0 >> 11);          // row / SEQ
        long rb = row0 & (SEQ - 1);
        bf16x4 pv;
#pragma unroll
        for (int r = 0; r < 4; ++r) pv[r] = (__bf16)(acc[i][j][r] + bb);
        *(bf16x4*)&((__bf16*)Cout)[((long)bz * N + col) * SEQ + rb] = pv;
      } else {
#pragma unroll
        for (int r = 0; r < 4; ++r) {
          long row = crow0 + i * 16 + r;
          float val = acc[i][j][r] + bb;
          if (OUTMODE == 0)
            ((float*)Cout)[row * N + col] = val;
          else
            ((__bf16*)Cout)[row * N + col] = (__bf16)val;
        }
      }
    }
  }
}

extern "C" void kernel_launch(void* const* d_in, const int* in_sizes, int n_in,
                              void* d_out, int out_size, void* d_ws, size_t ws_size,
                              hipStream_t stream) {
  const float* x = (const float*)d_in[0];
  const float* Wq = (const float*)d_in[1];
  const float* bq = (const float*)d_in[2];
  const float* Wk = (const float*)d_in[3];
  const float* bk = (const float*)d_in[4];
  const float* Wv = (const float*)d_in[5];
  const float* bv = (const float*)d_in[6];
  const float* We = (const float*)d_in[7];
  const float* be = (const float*)d_in[8];
  const float* Wo = (const float*)d_in[9];
  const float* bo = (const float*)d_in[10];
  float* out = (float*)d_out;

  char* ws = (char*)d_ws;
  size_t o = 0;
  auto alloc = [&](size_t n) {
    size_t r = o;
    o += (n + 255) & ~(size_t)255;
    return r;
  };
  __bf16* xbf = (__bf16*)(ws + alloc((size_t)MROWS * H * 2));  // x hi
  __bf16* v_t = (__bf16*)(ws + alloc((size_t)MROWS * H * 2));  // v^T [B][H][S]
  __bf16* attn = (__bf16*)(ws + alloc((size_t)MROWS * H * 2));
  __bf16* Wvt = (__bf16*)(ws + alloc((size_t)H * H * 2));
  __bf16* Wot = (__bf16*)(ws + alloc((size_t)H * H * 2));
  __bf16* Cth = (__bf16*)(ws + alloc((size_t)32 * H * 2));
  __bf16* Ctl = (__bf16*)(ws + alloc((size_t)32 * H * 2));
  float* dvec = (float*)(ws + alloc(32 * 4));
  __bf16* qq32 = (__bf16*)(ws + alloc((size_t)MROWS * 32 * 2));
  __bf16* kk32 = (__bf16*)(ws + alloc((size_t)MROWS * 32 * 2));
  // Alias (stream-ordered lifetime separation):
  __bf16* xlo = attn;  // x lo part: dead before attn is written (fused_attn)
  if (ws_size < o) return;

  // 1) merged prep v2: {cqk, dvec} first (latency, overlap), then transposes,
  //    then cvt_split streaming bulk (bf16x8 stores)
  prep_all<<<6657, 256, 0, stream>>>(x, xbf, xlo, Wv, Wvt, Wo, Wot, Wq, Wk,
                                     We, Cth, Ctl, bq, bk, be, dvec);
  // 2) unit-norm quantum embeds via MFMA (4-way K-split, 16 waves)
  k3_embed_mfma<<<MROWS / 32, 1024, 0, stream>>>(xbf, xlo, Cth, Ctl, dvec, qq32, kk32);
  // 3) v = x@Wv + bv, written TRANSPOSED per batch -> v_t[b][h][s]
  gemm_bt<2, 1><<<dim3(8, 64), 256, 0, stream>>>(xbf, Wvt, v_t, bv, MROWS, H, H);
  // 4) fused: S^T once per 256h -> exp2(S'^2) -> P@v/rowsum (8 waves)
  fused_attn<<<256, 512, 0, stream>>>(qq32, kk32, v_t, attn);
  // 5) out = attended @ Wo + bo  (fp32 out)
  gemm_bt<0, 1><<<dim3(8, 64), 256, 0, stream>>>(attn, Wot, out, bo, MROWS, H, H);
}